// Round 6
// baseline (1722.080 us; speedup 1.0000x reference)
//
#include <hip/hip_runtime.h>
#include <hip/hip_fp16.h>
#include <hip/hip_cooperative_groups.h>
#include <stdint.h>

namespace cg = cooperative_groups;

#define NROWS 8192
#define DIM 64
#define EPS 0.1f

typedef float f32x4 __attribute__((ext_vector_type(4)));
typedef short s16x8 __attribute__((ext_vector_type(8)));
typedef _Float16 h2 __attribute__((ext_vector_type(2)));

// ---------- helpers ----------

__device__ __forceinline__ float wave_reduce_add(float v) {
  #pragma unroll
  for (int off = 32; off > 0; off >>= 1) v += __shfl_down(v, off, 64);
  return v;
}

__device__ __forceinline__ unsigned short f2bf(float f) {
  uint32_t u = __float_as_uint(f);
  return (unsigned short)((u + 0x7fffu + ((u >> 16) & 1u)) >> 16);
}

// float in (0,1] -> fp8 e5m2 byte (OCP), RNE: f32->f16 (HW RNE), then RNE top byte.
__device__ __forceinline__ uint32_t f2e5m2(float f) {
  uint32_t h = (uint32_t)__half_as_ushort(__float2half(f));
  return (h + 0x7Fu + ((h >> 8) & 1u)) >> 8;
}

// e5m2 byte (already shifted: byte<<8) -> float via f16 reinterpret
__device__ __forceinline__ float e5m2f(uint32_t hbits) {
  return __half2float(__ushort_as_half((unsigned short)hbits));
}

// Packed f16 pair from two e5m2 bytes of wd (byte<<8 == exact f16).
#define SEL01 0x01040004u
#define SEL23 0x03040204u
__device__ __forceinline__ h2 kpair(uint32_t wd, uint32_t sel) {
  return __builtin_bit_cast(h2, __builtin_amdgcn_perm(0u, wd, sel));
}

// ---------- small kernels ----------

__global__ __launch_bounds__(256) void rownorm_kernel(
    const float* __restrict__ P, const float* __restrict__ Q,
    float* __restrict__ p2, float* __restrict__ q2) {
  int wid  = threadIdx.x >> 6;
  int lane = threadIdx.x & 63;
  int row  = blockIdx.x * 4 + wid;  // 0..16383
  const float* X;
  float* out;
  int r;
  if (row < NROWS) { X = P; out = p2; r = row; }
  else             { X = Q; out = q2; r = row - NROWS; }
  float v = X[(size_t)r * DIM + lane];
  float s = wave_reduce_add(v * v);
  if (lane == 0) out[r] = s;
}

__global__ void init_u_kernel(float* __restrict__ u) {
  int i = blockIdx.x * blockDim.x + threadIdx.x;
  if (i < NROWS) u[i] = 1.0f / 64.0f;
}

// ---------- kgen: MFMA bf16, 128x128 tile, fp8 e5m2 dword stores ----------

struct KgenSmem {
  unsigned char A[128 * 128];   // -2P tile, bf16, swizzled
  unsigned char B[128 * 128];   // Q tile, bf16, swizzled
  float p2s[128];
  float q2s[128];
};

__device__ __forceinline__ int swiz_off(int row, int kc) {
  return row * 128 + ((kc ^ (row & 7)) << 4);
}

__global__ __launch_bounds__(256) void kgen_kernel(
    const float* __restrict__ P, const float* __restrict__ Q,
    const float* __restrict__ p2, const float* __restrict__ q2,
    unsigned char* __restrict__ K) {
  __shared__ KgenSmem sm;
  const int t  = threadIdx.x;
  const int bi = blockIdx.y * 128;
  const int bj = blockIdx.x * 128;

  {
    const float4* P4 = (const float4*)(P + (size_t)bi * DIM);
    const float4* Q4 = (const float4*)(Q + (size_t)bj * DIM);
    #pragma unroll
    for (int it = 0; it < 4; ++it) {
      int idx = t + it * 256;
      int row = idx >> 3;
      int kc  = idx & 7;
      int g   = row * 16 + kc * 2;
      float4 a0 = P4[g], a1 = P4[g + 1];
      float4 b0 = Q4[g], b1 = Q4[g + 1];
      uint4 pa, pb;
      pa.x = f2bf(-2.f * a0.x) | ((uint32_t)f2bf(-2.f * a0.y) << 16);
      pa.y = f2bf(-2.f * a0.z) | ((uint32_t)f2bf(-2.f * a0.w) << 16);
      pa.z = f2bf(-2.f * a1.x) | ((uint32_t)f2bf(-2.f * a1.y) << 16);
      pa.w = f2bf(-2.f * a1.z) | ((uint32_t)f2bf(-2.f * a1.w) << 16);
      pb.x = f2bf(b0.x) | ((uint32_t)f2bf(b0.y) << 16);
      pb.y = f2bf(b0.z) | ((uint32_t)f2bf(b0.w) << 16);
      pb.z = f2bf(b1.x) | ((uint32_t)f2bf(b1.y) << 16);
      pb.w = f2bf(b1.z) | ((uint32_t)f2bf(b1.w) << 16);
      *(uint4*)(sm.A + swiz_off(row, kc)) = pa;
      *(uint4*)(sm.B + swiz_off(row, kc)) = pb;
    }
    if (t < 128)                   sm.p2s[t]       = p2[bi + t];
    else                           sm.q2s[t - 128] = q2[bj + t - 128];
  }
  __syncthreads();

  const int w        = t >> 6;
  const int lane     = t & 63;
  const int quad     = lane >> 4;
  const int m16      = lane & 15;
  const int wave_row = (w >> 1) * 64;
  const int wave_col = (w & 1) * 64;

  float pn[4];
  f32x4 qn[4];
  #pragma unroll
  for (int ti = 0; ti < 4; ++ti) pn[ti] = sm.p2s[wave_row + ti * 16 + m16];
  #pragma unroll
  for (int tj = 0; tj < 4; ++tj)
    qn[tj] = *(const f32x4*)&sm.q2s[wave_col + tj * 16 + quad * 4];

  f32x4 acc[4][4];
  #pragma unroll
  for (int ti = 0; ti < 4; ++ti)
    #pragma unroll
    for (int tj = 0; tj < 4; ++tj) acc[ti][tj] = qn[tj] + pn[ti];

  #pragma unroll
  for (int kstep = 0; kstep < 2; ++kstep) {
    const int kc = kstep * 4 + quad;
    s16x8 af[4], bf[4];
    #pragma unroll
    for (int ti = 0; ti < 4; ++ti)
      af[ti] = *(const s16x8*)(sm.A + swiz_off(wave_row + ti * 16 + m16, kc));
    #pragma unroll
    for (int tj = 0; tj < 4; ++tj)
      bf[tj] = *(const s16x8*)(sm.B + swiz_off(wave_col + tj * 16 + m16, kc));
    #pragma unroll
    for (int ti = 0; ti < 4; ++ti)
      #pragma unroll
      for (int tj = 0; tj < 4; ++tj)
        acc[ti][tj] = __builtin_amdgcn_mfma_f32_16x16x32_bf16(
            bf[tj], af[ti], acc[ti][tj], 0, 0, 0);   // swapped operands
  }

  #pragma unroll
  for (int ti = 0; ti < 4; ++ti) {
    unsigned char* rowp =
        K + (size_t)(bi + wave_row + ti * 16 + m16) * NROWS + bj + wave_col + quad * 4;
    #pragma unroll
    for (int tj = 0; tj < 4; ++tj) {
      f32x4 sq = acc[ti][tj];
      float k0 = __expf(-10.f * __builtin_amdgcn_sqrtf(fmaxf(sq.x, 0.f)));
      float k1 = __expf(-10.f * __builtin_amdgcn_sqrtf(fmaxf(sq.y, 0.f)));
      float k2 = __expf(-10.f * __builtin_amdgcn_sqrtf(fmaxf(sq.z, 0.f)));
      float k3 = __expf(-10.f * __builtin_amdgcn_sqrtf(fmaxf(sq.w, 0.f)));
      uint32_t word = f2e5m2(k0) | (f2e5m2(k1) << 8) |
                      (f2e5m2(k2) << 16) | (f2e5m2(k3) << 24);
      *(uint32_t*)(rowp + tj * 16) = word;
    }
  }
}

// ---------- persistent Sinkhorn v2: 1024 blocks, 2 rows/wave, x from LDS ----------

#define MV_DOT(d, xlo, xhi, accA, accB)                                              \
  accA = __builtin_amdgcn_fdot2(kpair((d), SEL01), __builtin_bit_cast(h2, (xlo)),    \
                                accA, false);                                        \
  accB = __builtin_amdgcn_fdot2(kpair((d), SEL23), __builtin_bit_cast(h2, (xhi)),    \
                                accB, false);

#define FN_DOT(d, xlo, xhi, s1, s2)                                                  \
  {                                                                                  \
    h2 k01 = kpair((d), SEL01), k23 = kpair((d), SEL23);                             \
    h2 x01 = __builtin_bit_cast(h2, (xlo)), x23 = __builtin_bit_cast(h2, (xhi));     \
    s1 = __builtin_amdgcn_fdot2(k01, x01, s1, false);                                \
    s1 = __builtin_amdgcn_fdot2(k23, x23, s1, false);                                \
    float kk;                                                                        \
    kk = (float)k01.x; s2 = fmaf(kk * (float)x01.x, __logf(fmaxf(kk, 1e-7f)), s2);   \
    kk = (float)k01.y; s2 = fmaf(kk * (float)x01.y, __logf(fmaxf(kk, 1e-7f)), s2);   \
    kk = (float)k23.x; s2 = fmaf(kk * (float)x23.x, __logf(fmaxf(kk, 1e-7f)), s2);   \
    kk = (float)k23.y; s2 = fmaf(kk * (float)x23.y, __logf(fmaxf(kk, 1e-7f)), s2);   \
  }

__global__ __launch_bounds__(256, 4) void sinkhorn_kernel(
    const unsigned char* __restrict__ K, float* __restrict__ ub,
    float* __restrict__ vb, float* __restrict__ partials,
    float* __restrict__ out) {
  cg::grid_group grid = cg::this_grid();
  __shared__ uint32_t xsh[NROWS / 2];   // 4096 packed f16 pairs = 16 KB
  __shared__ float sred[4];
  const int t    = threadIdx.x;
  const int lane = t & 63;
  const int w    = t >> 6;
  const int row0 = blockIdx.x * 8 + w * 2;   // 1024 blocks * 4 waves * 2 rows

  #pragma unroll 1
  for (int m = 0; m < 10; ++m) {
    if (m > 0) {
      grid.sync();                       // previous pass's y fully visible
      const float* xin = (m & 1) ? vb : ub;
      const float4* x4 = (const float4*)xin;
      #pragma unroll
      for (int i = 0; i < 8; ++i) {
        float4 xv = x4[t + i * 256];
        uint32_t lo = __builtin_bit_cast(
            uint32_t, __builtin_amdgcn_cvt_pkrtz(xv.x, xv.y));
        uint32_t hi = __builtin_bit_cast(
            uint32_t, __builtin_amdgcn_cvt_pkrtz(xv.z, xv.w));
        *(uint2*)&xsh[2 * t + 512 * i] = uint2{lo, hi};
      }
      __syncthreads();
    }

    // Load both rows' K up-front: 16 outstanding dwordx4 loads per lane.
    const uint4* k40 = (const uint4*)(K + (size_t)row0 * NROWS);
    const uint4* k41 = (const uint4*)(K + (size_t)(row0 + 1) * NROWS);
    uint4 kw0[8], kw1[8];
    #pragma unroll
    for (int s = 0; s < 8; ++s) kw0[s] = k40[s * 64 + lane];
    #pragma unroll
    for (int s = 0; s < 8; ++s) kw1[s] = k41[s * 64 + lane];

    float* yout = (m & 1) ? ub : vb;

    if (m == 0) {
      // u0 = const/64: y = 64 / rowsum
      const h2 one2 = (h2){(_Float16)1.f, (_Float16)1.f};
      float a0 = 0.f, a1 = 0.f, b0 = 0.f, b1 = 0.f;
      #pragma unroll
      for (int s = 0; s < 8; ++s) {
        a0 = __builtin_amdgcn_fdot2(kpair(kw0[s].x, SEL01), one2, a0, false);
        a1 = __builtin_amdgcn_fdot2(kpair(kw0[s].x, SEL23), one2, a1, false);
        a0 = __builtin_amdgcn_fdot2(kpair(kw0[s].y, SEL01), one2, a0, false);
        a1 = __builtin_amdgcn_fdot2(kpair(kw0[s].y, SEL23), one2, a1, false);
        a0 = __builtin_amdgcn_fdot2(kpair(kw0[s].z, SEL01), one2, a0, false);
        a1 = __builtin_amdgcn_fdot2(kpair(kw0[s].z, SEL23), one2, a1, false);
        a0 = __builtin_amdgcn_fdot2(kpair(kw0[s].w, SEL01), one2, a0, false);
        a1 = __builtin_amdgcn_fdot2(kpair(kw0[s].w, SEL23), one2, a1, false);
        b0 = __builtin_amdgcn_fdot2(kpair(kw1[s].x, SEL01), one2, b0, false);
        b1 = __builtin_amdgcn_fdot2(kpair(kw1[s].x, SEL23), one2, b1, false);
        b0 = __builtin_amdgcn_fdot2(kpair(kw1[s].y, SEL01), one2, b0, false);
        b1 = __builtin_amdgcn_fdot2(kpair(kw1[s].y, SEL23), one2, b1, false);
        b0 = __builtin_amdgcn_fdot2(kpair(kw1[s].z, SEL01), one2, b0, false);
        b1 = __builtin_amdgcn_fdot2(kpair(kw1[s].z, SEL23), one2, b1, false);
        b0 = __builtin_amdgcn_fdot2(kpair(kw1[s].w, SEL01), one2, b0, false);
        b1 = __builtin_amdgcn_fdot2(kpair(kw1[s].w, SEL23), one2, b1, false);
      }
      float s0 = wave_reduce_add(a0 + a1);
      float s1 = wave_reduce_add(b0 + b1);
      if (lane == 0) {
        yout[row0]     = 64.f / s0;
        yout[row0 + 1] = 64.f / s1;
      }
    } else if (m < 9) {
      float a0 = 0.f, a1 = 0.f, a2 = 0.f, a3 = 0.f;
      float b0 = 0.f, b1 = 0.f, b2 = 0.f, b3 = 0.f;
      #pragma unroll
      for (int s = 0; s < 8; ++s) {
        int base = (s * 64 + lane) * 8;
        uint4 xa = *(const uint4*)&xsh[base];
        uint4 xb = *(const uint4*)&xsh[base + 4];
        MV_DOT(kw0[s].x, xa.x, xa.y, a0, a1)
        MV_DOT(kw0[s].y, xa.z, xa.w, a2, a3)
        MV_DOT(kw0[s].z, xb.x, xb.y, a0, a1)
        MV_DOT(kw0[s].w, xb.z, xb.w, a2, a3)
        MV_DOT(kw1[s].x, xa.x, xa.y, b0, b1)
        MV_DOT(kw1[s].y, xa.z, xa.w, b2, b3)
        MV_DOT(kw1[s].z, xb.x, xb.y, b0, b1)
        MV_DOT(kw1[s].w, xb.z, xb.w, b2, b3)
      }
      float s0 = wave_reduce_add((a0 + a1) + (a2 + a3));
      float s1 = wave_reduce_add((b0 + b1) + (b2 + b3));
      if (lane == 0) {
        yout[row0]     = 1.0f / s0;
        yout[row0 + 1] = 1.0f / s1;
      }
    } else {
      // final: per row, s1 = K v, s2 = sum K*v*ln(K); loss_row = -EPS*s2/s1
      float p0 = 0.f, q0 = 0.f, p1 = 0.f, q1 = 0.f;
      #pragma unroll
      for (int s = 0; s < 8; ++s) {
        int base = (s * 64 + lane) * 8;
        uint4 xa = *(const uint4*)&xsh[base];
        uint4 xb = *(const uint4*)&xsh[base + 4];
        FN_DOT(kw0[s].x, xa.x, xa.y, p0, q0)
        FN_DOT(kw0[s].y, xa.z, xa.w, p0, q0)
        FN_DOT(kw0[s].z, xb.x, xb.y, p0, q0)
        FN_DOT(kw0[s].w, xb.z, xb.w, p0, q0)
        FN_DOT(kw1[s].x, xa.x, xa.y, p1, q1)
        FN_DOT(kw1[s].y, xa.z, xa.w, p1, q1)
        FN_DOT(kw1[s].z, xb.x, xb.y, p1, q1)
        FN_DOT(kw1[s].w, xb.z, xb.w, p1, q1)
      }
      p0 = wave_reduce_add(p0);
      q0 = wave_reduce_add(q0);
      p1 = wave_reduce_add(p1);
      q1 = wave_reduce_add(q1);
      if (lane == 0) sred[w] = (-EPS) * (q0 / p0 + q1 / p1);
      __syncthreads();
      if (t == 0) partials[blockIdx.x] = sred[0] + sred[1] + sred[2] + sred[3];
    }
  }

  grid.sync();
  if (blockIdx.x == 0) {
    float s = partials[t] + partials[t + 256] + partials[t + 512] + partials[t + 768];
    s = wave_reduce_add(s);
    __shared__ float fred[4];
    if (lane == 0) fred[w] = s;
    __syncthreads();
    if (t == 0) out[0] = fred[0] + fred[1] + fred[2] + fred[3];
  }
}

// ---------- fallback (non-cooperative) chain ----------

__global__ __launch_bounds__(256) void matvec_kernel(
    const unsigned char* __restrict__ K, const float* __restrict__ x,
    float* __restrict__ y) {
  const int row = blockIdx.x;
  const uint4* krow = (const uint4*)(K + (size_t)row * NROWS);
  const int t = threadIdx.x;
  float acc = 0.f;
  #pragma unroll
  for (int s = 0; s < 2; ++s) {
    int idx = t + s * 256;
    uint4 kw = krow[idx];
    const float4* x4 = (const float4*)(x + idx * 16);
    float4 x0 = x4[0], x1 = x4[1], x2 = x4[2], x3 = x4[3];
    uint32_t wd;
    wd = kw.x;
    acc += e5m2f((wd << 8) & 0xff00u)  * x0.x + e5m2f(wd & 0xff00u)         * x0.y
         + e5m2f((wd >> 8) & 0xff00u)  * x0.z + e5m2f((wd >> 16) & 0xff00u) * x0.w;
    wd = kw.y;
    acc += e5m2f((wd << 8) & 0xff00u)  * x1.x + e5m2f(wd & 0xff00u)         * x1.y
         + e5m2f((wd >> 8) & 0xff00u)  * x1.z + e5m2f((wd >> 16) & 0xff00u) * x1.w;
    wd = kw.z;
    acc += e5m2f((wd << 8) & 0xff00u)  * x2.x + e5m2f(wd & 0xff00u)         * x2.y
         + e5m2f((wd >> 8) & 0xff00u)  * x2.z + e5m2f((wd >> 16) & 0xff00u) * x2.w;
    wd = kw.w;
    acc += e5m2f((wd << 8) & 0xff00u)  * x3.x + e5m2f(wd & 0xff00u)         * x3.y
         + e5m2f((wd >> 8) & 0xff00u)  * x3.z + e5m2f((wd >> 16) & 0xff00u) * x3.w;
  }
  acc = wave_reduce_add(acc);
  __shared__ float red[4];
  int lane = t & 63, wid = t >> 6;
  if (lane == 0) red[wid] = acc;
  __syncthreads();
  if (t == 0) y[row] = 1.0f / (red[0] + red[1] + red[2] + red[3]);
}

__global__ __launch_bounds__(256) void final_kernel(
    const unsigned char* __restrict__ K, const float* __restrict__ v,
    float* __restrict__ partials) {
  const int row = blockIdx.x;
  const uint4* krow = (const uint4*)(K + (size_t)row * NROWS);
  const int t = threadIdx.x;
  float s1 = 0.f, s2 = 0.f;
  #pragma unroll
  for (int s = 0; s < 2; ++s) {
    int idx = t + s * 256;
    uint4 kw = krow[idx];
    const float4* v4 = (const float4*)(v + idx * 16);
    float4 xv[4] = {v4[0], v4[1], v4[2], v4[3]};
    uint32_t wds[4] = {kw.x, kw.y, kw.z, kw.w};
    #pragma unroll
    for (int q = 0; q < 4; ++q) {
      uint32_t wd = wds[q];
      float kk[4] = {e5m2f((wd << 8) & 0xff00u), e5m2f(wd & 0xff00u),
                     e5m2f((wd >> 8) & 0xff00u), e5m2f((wd >> 16) & 0xff00u)};
      float xs[4] = {xv[q].x, xv[q].y, xv[q].z, xv[q].w};
      #pragma unroll
      for (int e = 0; e < 4; ++e) {
        float kv = kk[e] * xs[e];
        s1 += kv;
        s2 = fmaf(kv, -EPS * __logf(fmaxf(kk[e], 1e-12f)), s2);
      }
    }
  }
  s1 = wave_reduce_add(s1);
  s2 = wave_reduce_add(s2);
  __shared__ float r1[4], r2[4];
  int lane = t & 63, wid = t >> 6;
  if (lane == 0) { r1[wid] = s1; r2[wid] = s2; }
  __syncthreads();
  if (t == 0)
    partials[row] = (r2[0] + r2[1] + r2[2] + r2[3]) / (r1[0] + r1[1] + r1[2] + r1[3]);
}

__global__ __launch_bounds__(256) void reduce_kernel(
    const float* __restrict__ partials, float* __restrict__ out) {
  const int t = threadIdx.x;
  float s = 0.f;
  #pragma unroll
  for (int i = 0; i < NROWS / 256; ++i) s += partials[t + i * 256];
  s = wave_reduce_add(s);
  __shared__ float red[4];
  int lane = t & 63, wid = t >> 6;
  if (lane == 0) red[wid] = s;
  __syncthreads();
  if (t == 0) out[0] = red[0] + red[1] + red[2] + red[3];
}

// ---------- launch ----------

extern "C" void kernel_launch(void* const* d_in, const int* in_sizes, int n_in,
                              void* d_out, int out_size, void* d_ws, size_t ws_size,
                              hipStream_t stream) {
  const float* P = (const float*)d_in[0];
  const float* Q = (const float*)d_in[1];
  float* out = (float*)d_out;

  char* ws = (char*)d_ws;
  unsigned char* K = (unsigned char*)ws;                 // 8192*8192 = 67108864 B
  float* p2 = (float*)(ws + (size_t)NROWS * NROWS);
  float* q2 = p2 + NROWS;
  float* ub = q2 + NROWS;
  float* vb = ub + NROWS;
  float* partials = vb + NROWS;                          // >= 8192 floats

  rownorm_kernel<<<(2 * NROWS) / 4, 256, 0, stream>>>(P, Q, p2, q2);
  kgen_kernel<<<dim3(NROWS / 128, NROWS / 128), 256, 0, stream>>>(P, Q, p2, q2, K);

  void* args[5] = {(void*)&K, (void*)&ub, (void*)&vb, (void*)&partials, (void*)&out};
  hipError_t err = hipLaunchCooperativeKernel((const void*)sinkhorn_kernel,
                                              dim3(1024), dim3(256), args, 0, stream);
  if (err != hipSuccess) {
    // Deterministic fallback: non-cooperative chain (round-3 structure).
    init_u_kernel<<<NROWS / 256, 256, 0, stream>>>(ub);
    for (int m = 0; m < 9; ++m) {
      const float* xin = (m & 1) ? vb : ub;
      float* yout      = (m & 1) ? ub : vb;
      matvec_kernel<<<NROWS, 256, 0, stream>>>(K, xin, yout);
    }
    final_kernel<<<NROWS, 256, 0, stream>>>(K, vb, partials);
    reduce_kernel<<<1, 256, 0, stream>>>(partials, out);
  }
}

// Round 7
// 268.837 us; speedup vs baseline: 6.4057x; 6.4057x over previous
//
#include <hip/hip_runtime.h>
#include <hip/hip_fp16.h>
#include <stdint.h>

#define NROWS 8192
#define DIM 64
#define EPS 0.1f

typedef float f32x4 __attribute__((ext_vector_type(4)));
typedef short s16x8 __attribute__((ext_vector_type(8)));
typedef _Float16 h2 __attribute__((ext_vector_type(2)));

// ---------- helpers ----------

__device__ __forceinline__ float wave_reduce_add(float v) {
  #pragma unroll
  for (int off = 32; off > 0; off >>= 1) v += __shfl_down(v, off, 64);
  return v;
}

__device__ __forceinline__ unsigned short f2bf(float f) {
  uint32_t u = __float_as_uint(f);
  return (unsigned short)((u + 0x7fffu + ((u >> 16) & 1u)) >> 16);
}

// float in (0,1] -> fp8 e5m2 byte (OCP), RNE: f32->f16 (HW RNE), then RNE top byte.
__device__ __forceinline__ uint32_t f2e5m2(float f) {
  uint32_t h = (uint32_t)__half_as_ushort(__float2half(f));
  return (h + 0x7Fu + ((h >> 8) & 1u)) >> 8;
}

// Packed f16 pair from two e5m2 bytes of wd (byte<<8 == exact f16).
#define SEL01 0x01040004u
#define SEL23 0x03040204u
__device__ __forceinline__ h2 kpair(uint32_t wd, uint32_t sel) {
  return __builtin_bit_cast(h2, __builtin_amdgcn_perm(0u, wd, sel));
}

#define MV_DOT(d, xlo, xhi, accA, accB)                                              \
  accA = __builtin_amdgcn_fdot2(kpair((d), SEL01), __builtin_bit_cast(h2, (xlo)),    \
                                accA, false);                                        \
  accB = __builtin_amdgcn_fdot2(kpair((d), SEL23), __builtin_bit_cast(h2, (xhi)),    \
                                accB, false);

#define FN_DOT(d, xlo, xhi, s1, s2)                                                  \
  {                                                                                  \
    h2 k01 = kpair((d), SEL01), k23 = kpair((d), SEL23);                             \
    h2 x01 = __builtin_bit_cast(h2, (xlo)), x23 = __builtin_bit_cast(h2, (xhi));     \
    s1 = __builtin_amdgcn_fdot2(k01, x01, s1, false);                                \
    s1 = __builtin_amdgcn_fdot2(k23, x23, s1, false);                                \
    float kk;                                                                        \
    kk = (float)k01.x; s2 = fmaf(kk * (float)x01.x, __logf(fmaxf(kk, 1e-7f)), s2);   \
    kk = (float)k01.y; s2 = fmaf(kk * (float)x01.y, __logf(fmaxf(kk, 1e-7f)), s2);   \
    kk = (float)k23.x; s2 = fmaf(kk * (float)x23.x, __logf(fmaxf(kk, 1e-7f)), s2);   \
    kk = (float)k23.y; s2 = fmaf(kk * (float)x23.y, __logf(fmaxf(kk, 1e-7f)), s2);   \
  }

// ---------- small kernels ----------

__global__ __launch_bounds__(256) void rownorm_kernel(
    const float* __restrict__ P, const float* __restrict__ Q,
    float* __restrict__ p2, float* __restrict__ q2) {
  int wid  = threadIdx.x >> 6;
  int lane = threadIdx.x & 63;
  int row  = blockIdx.x * 4 + wid;  // 0..16383
  const float* X;
  float* out;
  int r;
  if (row < NROWS) { X = P; out = p2; r = row; }
  else             { X = Q; out = q2; r = row - NROWS; }
  float v = X[(size_t)r * DIM + lane];
  float s = wave_reduce_add(v * v);
  if (lane == 0) out[r] = s;
}

__global__ void init_u_kernel(float* __restrict__ u) {
  int i = blockIdx.x * blockDim.x + threadIdx.x;
  if (i < NROWS) u[i] = 1.0f / 64.0f;
}

// ---------- kgen: MFMA bf16, 128x128 tile, fp8 e5m2 dword stores ----------

struct KgenSmem {
  unsigned char A[128 * 128];   // -2P tile, bf16, swizzled
  unsigned char B[128 * 128];   // Q tile, bf16, swizzled
  float p2s[128];
  float q2s[128];
};

__device__ __forceinline__ int swiz_off(int row, int kc) {
  return row * 128 + ((kc ^ (row & 7)) << 4);
}

__global__ __launch_bounds__(256) void kgen_kernel(
    const float* __restrict__ P, const float* __restrict__ Q,
    const float* __restrict__ p2, const float* __restrict__ q2,
    unsigned char* __restrict__ K) {
  __shared__ KgenSmem sm;
  const int t  = threadIdx.x;
  const int bi = blockIdx.y * 128;
  const int bj = blockIdx.x * 128;

  {
    const float4* P4 = (const float4*)(P + (size_t)bi * DIM);
    const float4* Q4 = (const float4*)(Q + (size_t)bj * DIM);
    #pragma unroll
    for (int it = 0; it < 4; ++it) {
      int idx = t + it * 256;
      int row = idx >> 3;
      int kc  = idx & 7;
      int g   = row * 16 + kc * 2;
      float4 a0 = P4[g], a1 = P4[g + 1];
      float4 b0 = Q4[g], b1 = Q4[g + 1];
      uint4 pa, pb;
      pa.x = f2bf(-2.f * a0.x) | ((uint32_t)f2bf(-2.f * a0.y) << 16);
      pa.y = f2bf(-2.f * a0.z) | ((uint32_t)f2bf(-2.f * a0.w) << 16);
      pa.z = f2bf(-2.f * a1.x) | ((uint32_t)f2bf(-2.f * a1.y) << 16);
      pa.w = f2bf(-2.f * a1.z) | ((uint32_t)f2bf(-2.f * a1.w) << 16);
      pb.x = f2bf(b0.x) | ((uint32_t)f2bf(b0.y) << 16);
      pb.y = f2bf(b0.z) | ((uint32_t)f2bf(b0.w) << 16);
      pb.z = f2bf(b1.x) | ((uint32_t)f2bf(b1.y) << 16);
      pb.w = f2bf(b1.z) | ((uint32_t)f2bf(b1.w) << 16);
      *(uint4*)(sm.A + swiz_off(row, kc)) = pa;
      *(uint4*)(sm.B + swiz_off(row, kc)) = pb;
    }
    if (t < 128)                   sm.p2s[t]       = p2[bi + t];
    else                           sm.q2s[t - 128] = q2[bj + t - 128];
  }
  __syncthreads();

  const int w        = t >> 6;
  const int lane     = t & 63;
  const int quad     = lane >> 4;
  const int m16      = lane & 15;
  const int wave_row = (w >> 1) * 64;
  const int wave_col = (w & 1) * 64;

  float pn[4];
  f32x4 qn[4];
  #pragma unroll
  for (int ti = 0; ti < 4; ++ti) pn[ti] = sm.p2s[wave_row + ti * 16 + m16];
  #pragma unroll
  for (int tj = 0; tj < 4; ++tj)
    qn[tj] = *(const f32x4*)&sm.q2s[wave_col + tj * 16 + quad * 4];

  f32x4 acc[4][4];
  #pragma unroll
  for (int ti = 0; ti < 4; ++ti)
    #pragma unroll
    for (int tj = 0; tj < 4; ++tj) acc[ti][tj] = qn[tj] + pn[ti];

  #pragma unroll
  for (int kstep = 0; kstep < 2; ++kstep) {
    const int kc = kstep * 4 + quad;
    s16x8 af[4], bf[4];
    #pragma unroll
    for (int ti = 0; ti < 4; ++ti)
      af[ti] = *(const s16x8*)(sm.A + swiz_off(wave_row + ti * 16 + m16, kc));
    #pragma unroll
    for (int tj = 0; tj < 4; ++tj)
      bf[tj] = *(const s16x8*)(sm.B + swiz_off(wave_col + tj * 16 + m16, kc));
    #pragma unroll
    for (int ti = 0; ti < 4; ++ti)
      #pragma unroll
      for (int tj = 0; tj < 4; ++tj)
        acc[ti][tj] = __builtin_amdgcn_mfma_f32_16x16x32_bf16(
            bf[tj], af[ti], acc[ti][tj], 0, 0, 0);   // swapped operands
  }

  #pragma unroll
  for (int ti = 0; ti < 4; ++ti) {
    unsigned char* rowp =
        K + (size_t)(bi + wave_row + ti * 16 + m16) * NROWS + bj + wave_col + quad * 4;
    #pragma unroll
    for (int tj = 0; tj < 4; ++tj) {
      f32x4 sq = acc[ti][tj];
      float k0 = __expf(-10.f * __builtin_amdgcn_sqrtf(fmaxf(sq.x, 0.f)));
      float k1 = __expf(-10.f * __builtin_amdgcn_sqrtf(fmaxf(sq.y, 0.f)));
      float k2 = __expf(-10.f * __builtin_amdgcn_sqrtf(fmaxf(sq.z, 0.f)));
      float k3 = __expf(-10.f * __builtin_amdgcn_sqrtf(fmaxf(sq.w, 0.f)));
      uint32_t word = f2e5m2(k0) | (f2e5m2(k1) << 8) |
                      (f2e5m2(k2) << 16) | (f2e5m2(k3) << 24);
      *(uint32_t*)(rowp + tj * 16) = word;
    }
  }
}

// ---------- matvec8: 8 rows/block, x staged once in LDS as f16 pairs ----------
// 1024 blocks x 256 thr. Wave w handles rows block*8 + 2w, 2w+1 (whole row per
// wave: 128 elems/lane = 8 uint4 K + 16 LDS uint4 x). y = 1/(K x) per row.

__global__ __launch_bounds__(256) void matvec8_kernel(
    const unsigned char* __restrict__ K, const float* __restrict__ x,
    float* __restrict__ y) {
  __shared__ uint32_t xsh[NROWS / 2];   // 16 KB packed f16 pairs
  const int t    = threadIdx.x;
  const int lane = t & 63;
  const int w    = t >> 6;

  const float4* x4 = (const float4*)x;
  #pragma unroll
  for (int i = 0; i < 8; ++i) {
    float4 xv = x4[t + i * 256];
    uint32_t lo = __builtin_bit_cast(uint32_t, __builtin_amdgcn_cvt_pkrtz(xv.x, xv.y));
    uint32_t hi = __builtin_bit_cast(uint32_t, __builtin_amdgcn_cvt_pkrtz(xv.z, xv.w));
    *(uint2*)&xsh[2 * t + 512 * i] = uint2{lo, hi};
  }
  __syncthreads();

  #pragma unroll 1
  for (int rr = 0; rr < 2; ++rr) {
    const int row = blockIdx.x * 8 + w * 2 + rr;
    const uint4* k4 = (const uint4*)(K + (size_t)row * NROWS);
    float a0 = 0.f, a1 = 0.f, a2 = 0.f, a3 = 0.f;
    #pragma unroll
    for (int s = 0; s < 8; ++s) {
      uint4 kw = k4[s * 64 + lane];
      int base = (s * 64 + lane) * 8;
      uint4 xa = *(const uint4*)&xsh[base];
      uint4 xb = *(const uint4*)&xsh[base + 4];
      MV_DOT(kw.x, xa.x, xa.y, a0, a1)
      MV_DOT(kw.y, xa.z, xa.w, a2, a3)
      MV_DOT(kw.z, xb.x, xb.y, a0, a1)
      MV_DOT(kw.w, xb.z, xb.w, a2, a3)
    }
    float s = wave_reduce_add((a0 + a1) + (a2 + a3));
    if (lane == 0) y[row] = 1.0f / s;
  }
}

// ---------- final8: fused 10th matvec + loss, 8 rows/block ----------
// per row i: s1 = sum K*v, s2 = sum K*v*ln(K); loss_i = -EPS*s2/s1.
// Block partial -> partials[blockIdx.x]; reduced by reduce_kernel.

__global__ __launch_bounds__(256) void final8_kernel(
    const unsigned char* __restrict__ K, const float* __restrict__ v,
    float* __restrict__ partials) {
  __shared__ uint32_t xsh[NROWS / 2];
  __shared__ float sred[4];
  const int t    = threadIdx.x;
  const int lane = t & 63;
  const int w    = t >> 6;

  const float4* x4 = (const float4*)v;
  #pragma unroll
  for (int i = 0; i < 8; ++i) {
    float4 xv = x4[t + i * 256];
    uint32_t lo = __builtin_bit_cast(uint32_t, __builtin_amdgcn_cvt_pkrtz(xv.x, xv.y));
    uint32_t hi = __builtin_bit_cast(uint32_t, __builtin_amdgcn_cvt_pkrtz(xv.z, xv.w));
    *(uint2*)&xsh[2 * t + 512 * i] = uint2{lo, hi};
  }
  __syncthreads();

  float wloss = 0.f;
  #pragma unroll 1
  for (int rr = 0; rr < 2; ++rr) {
    const int row = blockIdx.x * 8 + w * 2 + rr;
    const uint4* k4 = (const uint4*)(K + (size_t)row * NROWS);
    float s1 = 0.f, s2 = 0.f;
    #pragma unroll
    for (int s = 0; s < 8; ++s) {
      uint4 kw = k4[s * 64 + lane];
      int base = (s * 64 + lane) * 8;
      uint4 xa = *(const uint4*)&xsh[base];
      uint4 xb = *(const uint4*)&xsh[base + 4];
      FN_DOT(kw.x, xa.x, xa.y, s1, s2)
      FN_DOT(kw.y, xa.z, xa.w, s1, s2)
      FN_DOT(kw.z, xb.x, xb.y, s1, s2)
      FN_DOT(kw.w, xb.z, xb.w, s1, s2)
    }
    s1 = wave_reduce_add(s1);
    s2 = wave_reduce_add(s2);
    if (lane == 0) wloss += (-EPS) * s2 / s1;
  }
  if (lane == 0) sred[w] = wloss;
  __syncthreads();
  if (t == 0) partials[blockIdx.x] = sred[0] + sred[1] + sred[2] + sred[3];
}

// Sum 1024 partials -> out[0].
__global__ __launch_bounds__(256) void reduce_kernel(
    const float* __restrict__ partials, float* __restrict__ out) {
  const int t = threadIdx.x;
  float s = partials[t] + partials[t + 256] + partials[t + 512] + partials[t + 768];
  s = wave_reduce_add(s);
  __shared__ float red[4];
  int lane = t & 63, wid = t >> 6;
  if (lane == 0) red[wid] = s;
  __syncthreads();
  if (t == 0) out[0] = red[0] + red[1] + red[2] + red[3];
}

// ---------- launch ----------

extern "C" void kernel_launch(void* const* d_in, const int* in_sizes, int n_in,
                              void* d_out, int out_size, void* d_ws, size_t ws_size,
                              hipStream_t stream) {
  const float* P = (const float*)d_in[0];
  const float* Q = (const float*)d_in[1];
  float* out = (float*)d_out;

  char* ws = (char*)d_ws;
  unsigned char* K = (unsigned char*)ws;                 // 8192*8192 = 67108864 B
  float* p2 = (float*)(ws + (size_t)NROWS * NROWS);
  float* q2 = p2 + NROWS;
  float* ub = q2 + NROWS;
  float* vb = ub + NROWS;
  float* partials = vb + NROWS;                          // >= 1024 floats

  rownorm_kernel<<<(2 * NROWS) / 4, 256, 0, stream>>>(P, Q, p2, q2);
  init_u_kernel<<<NROWS / 256, 256, 0, stream>>>(ub);
  kgen_kernel<<<dim3(NROWS / 128, NROWS / 128), 256, 0, stream>>>(P, Q, p2, q2, K);

  // 9 matvec passes; the 10th is fused into final8_kernel.
  for (int m = 0; m < 9; ++m) {
    const float* xin = (m & 1) ? vb : ub;
    float* yout      = (m & 1) ? ub : vb;
    matvec8_kernel<<<NROWS / 8, 256, 0, stream>>>(K, xin, yout);
  }

  final8_kernel<<<NROWS / 8, 256, 0, stream>>>(K, vb, partials);
  reduce_kernel<<<1, 256, 0, stream>>>(partials, out);
}